// Round 5
// baseline (380.990 us; speedup 1.0000x reference)
//
#include <hip/hip_runtime.h>
#include <hip/hip_bf16.h>

#define SEQ   512
#define BATCH 4096
#define NS    16
#define NO    8
#define NI    4
#define NK    12          // exact Riccati steps; steady-state gain after
#define CH    16          // time chunks
#define CL    (SEQ/CH)    // 32 steps per chunk
#define CW    16          // warm-up steps (state forgets init at ~0.6/step)

// per-step coefficient block: M(16x16) @0, N(16x4) @256, K(16x8) @320 -> 448 f32
__device__ float g_gains[NK * 448];
__device__ float g_x0[NS];

// ---------------- kernel 1: Riccati gain precompute, ONE WAVE ----------------
// R4 post-mortem: 256-thread version cost ~200us — ~340 cross-SIMD barriers
// dominated. Single wave => barriers are ~free; work is trivial.
// All inputs proven fp32 (R1 NaN with bf16 parse; R4 passed with fp32 parse).
__global__ __launch_bounds__(64) void riccati_kernel(
        const float* __restrict__ Apt, const float* __restrict__ Bpt,
        const float* __restrict__ Cpt, const float* __restrict__ Qpt,
        const float* __restrict__ Rpt, const float* __restrict__ x0pt) {
    __shared__ float A[256], Bm[64], Cm[128], Q[256], R[64];
    __shared__ float P[256], AP[256], Pp[256], CP[128];
    __shared__ float G[128], PCt[128], K[128], CA[128], CB[32], Pn[256];
    const int t = threadIdx.x;   // 64 threads

    for (int idx = t; idx < 256; idx += 64) {
        A[idx] = Apt[idx]; Q[idx] = Qpt[idx];
        P[idx] = ((idx >> 4) == (idx & 15)) ? 1.0f : 0.0f;   // P0 = I
    }
    Bm[t] = Bpt[t]; R[t] = Rpt[t];
    for (int idx = t; idx < 128; idx += 64) Cm[idx] = Cpt[idx];
    if (t < 16) g_x0[t] = x0pt[t];
    __syncthreads();

    // constants: CA = C@A (8x16), CB = C@B (8x4)
    for (int idx = t; idx < 128; idx += 64) {
        int i = idx >> 4, j = idx & 15; float acc = 0.f;
        for (int l = 0; l < 16; ++l) acc += Cm[i*16+l] * A[l*16+j];
        CA[idx] = acc;
    }
    if (t < 32) {
        int i = t >> 2, j = t & 3; float acc = 0.f;
        for (int l = 0; l < 16; ++l) acc += Cm[i*16+l] * Bm[l*4+j];
        CB[t] = acc;
    }
    __syncthreads();

    for (int k = 0; k < NK; ++k) {
        for (int idx = t; idx < 256; idx += 64) {   // AP = A @ P
            int i = idx >> 4, j = idx & 15; float a = 0.f;
            for (int l = 0; l < 16; ++l) a += A[i*16+l] * P[l*16+j];
            AP[idx] = a;
        }
        __syncthreads();
        for (int idx = t; idx < 256; idx += 64) {   // Pp = AP @ A^T + Q
            int i = idx >> 4, j = idx & 15; float a = Q[idx];
            for (int l = 0; l < 16; ++l) a += AP[i*16+l] * A[j*16+l];
            Pp[idx] = a;
        }
        __syncthreads();
        for (int idx = t; idx < 128; idx += 64) {   // CP = C @ Pp (8x16)
            int i = idx >> 4, j = idx & 15; float a = 0.f;
            for (int l = 0; l < 16; ++l) a += Cm[i*16+l] * Pp[l*16+j];
            CP[idx] = a;
        }
        __syncthreads();
        for (int idx = t; idx < 128; idx += 64) {   // G = [S | I], S = CP@C^T + R
            int i = idx >> 4, j = idx & 15; float a;
            if (j < 8) { a = R[i*8+j]; for (int l = 0; l < 16; ++l) a += CP[i*16+l] * Cm[j*16+l]; }
            else a = ((j - 8) == i) ? 1.0f : 0.0f;
            G[idx] = a;
        }
        __syncthreads();
        // Gauss-Jordan inverse (S SPD, no pivoting). Cells t and t+64 per lane;
        // all reads precede all writes in wave-lockstep program order.
        for (int p = 0; p < 8; ++p) {
            const int i0 = t >> 4, j0 = t & 15, i1 = i0 + 4;
            float piv = G[p*16+p];
            float gp  = G[p*16+j0];
            float gi0 = G[i0*16+p], gv0 = G[i0*16+j0];
            float gi1 = G[i1*16+p], gv1 = G[i1*16+j0];
            __syncthreads();
            float r = gp / piv;
            G[i0*16+j0] = (i0 == p) ? r : (gv0 - gi0 * r);
            G[i1*16+j0] = (i1 == p) ? r : (gv1 - gi1 * r);
            __syncthreads();
        }
        for (int idx = t; idx < 128; idx += 64) {   // PCt = Pp @ C^T (16x8)
            int i = idx >> 3, j = idx & 7; float a = 0.f;
            for (int l = 0; l < 16; ++l) a += Pp[i*16+l] * Cm[j*16+l];
            PCt[idx] = a;
        }
        __syncthreads();
        for (int idx = t; idx < 128; idx += 64) {   // K = PCt @ Sinv
            int i = idx >> 3, j = idx & 7; float a = 0.f;
            for (int l = 0; l < 8; ++l) a += PCt[i*8+l] * G[l*16+8+j];
            K[idx] = a;
        }
        __syncthreads();
        // emit: M = A - K@CA, N = B - K@CB, K; next P = Pp - K@CP
        float* outp = g_gains + k * 448;
        for (int idx = t; idx < 256; idx += 64) {
            int i = idx >> 4, j = idx & 15; float a = A[idx];
            for (int l = 0; l < 8; ++l) a -= K[i*8+l] * CA[l*16+j];
            outp[idx] = a;
        }
        {   int i = t >> 2, j = t & 3; float a = Bm[t];
            for (int l = 0; l < 8; ++l) a -= K[i*8+l] * CB[l*4+j];
            outp[256 + t] = a;
        }
        for (int idx = t; idx < 128; idx += 64) outp[320 + idx] = K[idx];
        for (int idx = t; idx < 256; idx += 64) {
            int i = idx >> 4, j = idx & 15; float a = Pp[idx];
            for (int l = 0; l < 8; ++l) a -= K[i*8+l] * CP[l*16+j];
            Pn[idx] = a;
        }
        __syncthreads();
        for (int idx = t; idx < 256; idx += 64) P[idx] = Pn[idx];
        __syncthreads();
    }
}

// ---------------- kernel 2: quad-per-batch affine recursion ----------------
// Lane l of each 4-lane quad owns state rows 4l..4l+3. Steady-state gains live
// in 112 VGPRs (zero reloads in hot loop). Cross-lane x broadcast via DPP
// quad_perm (VALU-speed). Data prefetch depth 2.
template<int CTRL>
static __device__ __forceinline__ float qrot(float v) {
    return __int_as_float(__builtin_amdgcn_mov_dpp(__float_as_int(v), CTRL, 0xf, 0xf, true));
}

__global__ __launch_bounds__(256) void filter_kernel(
        const float* __restrict__ obs, const float* __restrict__ u,
        float* __restrict__ out) {
    const int t    = threadIdx.x;
    const int lane = t & 3;
    const int c    = blockIdx.x >> 6;          // 64 blocks per chunk
    const int bg   = blockIdx.x & 63;
    const int b    = bg * 64 + (t >> 2);
    const int cL   = c * CL;
    const int k0   = (c == 0) ? 0 : (cL - CW);
    const int kend = cL + CL;

    float4 Mv[4][4], Nv[4], Kv[4][2];
    auto load_gains = [&](int idx) {
        const float* g = g_gains + idx * 448;
        const int row0 = 4 * lane;
#pragma unroll
        for (int i = 0; i < 4; ++i) {
            const float* mrow = g + (row0 + i) * 16;
#pragma unroll
            for (int r = 0; r < 4; ++r)
                Mv[i][r] = *(const float4*)(mrow + 4 * ((lane + r) & 3));
            Nv[i]    = *(const float4*)(g + 256 + (row0 + i) * 4);
            Kv[i][0] = *(const float4*)(g + 320 + (row0 + i) * 8);
            Kv[i][1] = *(const float4*)(g + 320 + (row0 + i) * 8 + 4);
        }
    };
    if (k0 >= NK) load_gains(NK - 1);          // steady-state chunks: load once

    float x[4];
#pragma unroll
    for (int i = 0; i < 4; ++i) x[i] = (c == 0) ? g_x0[4*lane + i] : 0.0f;

    const float* up = u   + (size_t)b * SEQ * NI;
    const float* zp = obs + (size_t)b * SEQ * NO;
    float*       op = out + (size_t)b * SEQ * NS + 4 * lane;

    float4 ub[2], z0b[2], z1b[2];
    {
        int ka = k0, kb = (k0 + 1 < kend) ? k0 + 1 : kend - 1;
        ub[0]  = *(const float4*)(up + ka * NI);
        z0b[0] = *(const float4*)(zp + ka * NO);
        z1b[0] = *(const float4*)(zp + ka * NO + 4);
        ub[1]  = *(const float4*)(up + kb * NI);
        z0b[1] = *(const float4*)(zp + kb * NO);
        z1b[1] = *(const float4*)(zp + kb * NO + 4);
    }

#pragma unroll 2
    for (int k = k0; k < kend; ++k) {
        const int p = (k - k0) & 1;
        if (k < NK) load_gains(k);             // chunk 0 only; wave-uniform
        float4 uc = ub[p], zc0 = z0b[p], zc1 = z1b[p];
        {   // prefetch k+2 into the slot we just freed
            int kf = (k + 2 < kend) ? k + 2 : kend - 1;
            ub[p]  = *(const float4*)(up + kf * NI);
            z0b[p] = *(const float4*)(zp + kf * NO);
            z1b[p] = *(const float4*)(zp + kf * NO + 4);
        }
        float acc[4];
#pragma unroll
        for (int i = 0; i < 4; ++i) {
            acc[i]  = Nv[i].x*uc.x  + Nv[i].y*uc.y  + Nv[i].z*uc.z  + Nv[i].w*uc.w;
            acc[i] += Kv[i][0].x*zc0.x + Kv[i][0].y*zc0.y + Kv[i][0].z*zc0.z + Kv[i][0].w*zc0.w;
            acc[i] += Kv[i][1].x*zc1.x + Kv[i][1].y*zc1.y + Kv[i][1].z*zc1.z + Kv[i][1].w*zc1.w;
            acc[i] += Mv[i][0].x*x[0] + Mv[i][0].y*x[1] + Mv[i][0].z*x[2] + Mv[i][0].w*x[3];
        }
        {   // rot 1: lane l reads lane (l+1)&3  (quad_perm [1,2,3,0] = 0x39)
            float y0 = qrot<0x39>(x[0]), y1 = qrot<0x39>(x[1]),
                  y2 = qrot<0x39>(x[2]), y3 = qrot<0x39>(x[3]);
#pragma unroll
            for (int i = 0; i < 4; ++i)
                acc[i] += Mv[i][1].x*y0 + Mv[i][1].y*y1 + Mv[i][1].z*y2 + Mv[i][1].w*y3;
        }
        {   // rot 2: [2,3,0,1] = 0x4E
            float y0 = qrot<0x4E>(x[0]), y1 = qrot<0x4E>(x[1]),
                  y2 = qrot<0x4E>(x[2]), y3 = qrot<0x4E>(x[3]);
#pragma unroll
            for (int i = 0; i < 4; ++i)
                acc[i] += Mv[i][2].x*y0 + Mv[i][2].y*y1 + Mv[i][2].z*y2 + Mv[i][2].w*y3;
        }
        {   // rot 3: [3,0,1,2] = 0x93
            float y0 = qrot<0x93>(x[0]), y1 = qrot<0x93>(x[1]),
                  y2 = qrot<0x93>(x[2]), y3 = qrot<0x93>(x[3]);
#pragma unroll
            for (int i = 0; i < 4; ++i)
                acc[i] += Mv[i][3].x*y0 + Mv[i][3].y*y1 + Mv[i][3].z*y2 + Mv[i][3].w*y3;
        }
#pragma unroll
        for (int i = 0; i < 4; ++i) x[i] = acc[i];

        if (k >= cL)   // quad writes 64 contiguous bytes
            *(float4*)(op + (size_t)k * NS) = make_float4(x[0], x[1], x[2], x[3]);
    }
}

extern "C" void kernel_launch(void* const* d_in, const int* in_sizes, int n_in,
                              void* d_out, int out_size, void* d_ws, size_t ws_size,
                              hipStream_t stream) {
    const float* obs = (const float*)d_in[0];
    const float* u   = (const float*)d_in[1];
    const float* A   = (const float*)d_in[2];
    const float* B   = (const float*)d_in[3];
    const float* C   = (const float*)d_in[4];
    const float* Q   = (const float*)d_in[5];
    const float* R   = (const float*)d_in[6];
    const float* x0  = (const float*)d_in[7];
    float* out = (float*)d_out;

    riccati_kernel<<<1, 64, 0, stream>>>(A, B, C, Q, R, x0);
    filter_kernel<<<dim3(CH * (BATCH*4/256)), dim3(256), 0, stream>>>(obs, u, out);
}